// Round 12
// baseline (122.011 us; speedup 1.0000x reference)
//
#include <hip/hip_runtime.h>

#define NN 2048

typedef unsigned short u16;
typedef unsigned char u8;
typedef __attribute__((ext_vector_type(4))) float floatx4;

// fp8 e4m3fn (positive-only domain here) -> f32
__device__ __forceinline__ float fp8_to_f32(unsigned v) {
  const unsigned e = (v >> 3) & 15, m = v & 7;
  const float norm = __uint_as_float(((e + 120u) << 23) | (m << 20));
  const float sub = (float)m * 0.001953125f;  // m * 2^-9
  return e == 0 ? sub : norm;
}

// async global->LDS, 16B per lane. LDS dest = wave-uniform base + lane*16.
__device__ __forceinline__ void load_lds16(const u8* g, const u8* l) {
  __builtin_amdgcn_global_load_lds(
      (const __attribute__((address_space(1))) unsigned int*)g,
      (__attribute__((address_space(3))) unsigned int*)(u8*)l,
      16, 0, 0);
}

// ---------------------------------------------------------------------------
// prep (R7-proven): fp32 -> fp8 e4m3 (A8 row-major + A8T transposed), fp32
// row-sum partials degp[mat][row][32], zero tri. HW cvt_pk_fp8 (RNE), 4x4
// register transpose, uint LDS pitch 17, coalesced stores.
// grid (32,32,2), block 256. Tile 64x64.
// ---------------------------------------------------------------------------
__global__ __launch_bounds__(256) void prep_kernel(
    const float* __restrict__ A1, const float* __restrict__ A2,
    u8* __restrict__ A8, u8* __restrict__ A8T,
    float* __restrict__ degp, float* __restrict__ tri) {
  __shared__ unsigned Tl[64 * 17];
  const int bx = blockIdx.x, by = blockIdx.y, bz = blockIdx.z;
  const float* __restrict__ A = bz ? A2 : A1;
  u8* __restrict__ ab = A8 + (size_t)bz * (NN * (size_t)NN);
  u8* __restrict__ at = A8T + (size_t)bz * (NN * (size_t)NN);
  float* __restrict__ dp = degp + (size_t)bz * (32 * NN);
  const int t = threadIdx.x;
  const int r0 = by * 64, c0 = bx * 64;
  const int q = t >> 4, cs = t & 15;

  if (bx == 0 && t < 64) tri[bz * NN + by * 64 + t] = 0.f;

  unsigned rowpack[4];
#pragma unroll
  for (int d = 0; d < 4; ++d) {
    const int r = 4 * q + d;
    const float4 fv = *(const float4*)(A + (size_t)(r0 + r) * NN + c0 + cs * 4);
    int pk = __builtin_amdgcn_cvt_pk_fp8_f32(fv.x, fv.y, 0, false);
    pk = __builtin_amdgcn_cvt_pk_fp8_f32(fv.z, fv.w, pk, true);
    rowpack[d] = (unsigned)pk;
    *(unsigned*)(ab + (size_t)(r0 + r) * NN + c0 + cs * 4) = (unsigned)pk;
    float s = fv.x + fv.y + fv.z + fv.w;
    s += __shfl_xor(s, 1); s += __shfl_xor(s, 2);
    s += __shfl_xor(s, 4); s += __shfl_xor(s, 8);
    if (cs == 0) dp[(size_t)(r0 + r) * 32 + bx] = s;
  }
#pragma unroll
  for (int e = 0; e < 4; ++e) {
    const unsigned tc = ((rowpack[0] >> (8 * e)) & 0xFFu) |
                        (((rowpack[1] >> (8 * e)) & 0xFFu) << 8) |
                        (((rowpack[2] >> (8 * e)) & 0xFFu) << 16) |
                        (((rowpack[3] >> (8 * e)) & 0xFFu) << 24);
    Tl[(4 * cs + e) * 17 + q] = tc;
  }
  __syncthreads();
#pragma unroll
  for (int p = 0; p < 2; ++p) {
    const int rp = p * 32 + (t >> 3);
    const int mm = t & 7;
    uint2 v;
    v.x = Tl[rp * 17 + 2 * mm];
    v.y = Tl[rp * 17 + 2 * mm + 1];
    *(uint2*)(at + (size_t)(c0 + rp) * NN + r0 + mm * 8) = v;
  }
}

#define FENCE asm volatile("" ::: "memory")

// stage one K-step (64 B x 64 rows of A and of B) into wave-private buffer PB
#define PREFETCH(KK, PB)                                                   \
  _Pragma("unroll")                                                        \
  for (int c = 0; c < 4; ++c) {                                            \
    load_lds16(gA[c] + (KK), wlds + (PB) + c * 1024);                      \
    load_lds16(gB[c] + (KK), wlds + (PB) + 4096 + c * 1024);               \
  }

#define MFMA_BODY(PB)                                                     \
  {                                                                       \
    long aL[4][2], bL[4][2];                                              \
    _Pragma("unroll")                                                     \
    for (int tm = 0; tm < 4; ++tm) {                                      \
      aL[tm][0] = *(const long*)(wlds + (PB) + aoff[tm][0]);              \
      aL[tm][1] = *(const long*)(wlds + (PB) + aoff[tm][1]);              \
    }                                                                     \
    _Pragma("unroll")                                                     \
    for (int tn = 0; tn < 4; ++tn) {                                      \
      bL[tn][0] = *(const long*)(wlds + (PB) + boff[tn][0]);              \
      bL[tn][1] = *(const long*)(wlds + (PB) + boff[tn][1]);              \
    }                                                                     \
    _Pragma("unroll")                                                     \
    for (int tm = 0; tm < 4; ++tm)                                        \
      _Pragma("unroll")                                                   \
      for (int tn = 0; tn < 4; ++tn) {                                    \
        acc[tm][tn] = __builtin_amdgcn_mfma_f32_16x16x32_fp8_fp8(         \
            aL[tm][0], bL[tn][0], acc[tm][tn], 0, 0, 0);                  \
        acc[tm][tn] = __builtin_amdgcn_mfma_f32_16x16x32_fp8_fp8(         \
            aL[tm][1], bL[tn][1], acc[tm][tn], 0, 0, 0);                  \
      }                                                                   \
  }

// ---------------------------------------------------------------------------
// gemm_tri fp8 v4 — BARRIER-FREE K-loop with WAVE-PRIVATE LDS staging.
// tri[i] += sum_j (A@A)_{ij} * A_{ji}. R5/R8/R9: the block-wide barrier per
// 64 B of K is the structural stall (~2000 cyc/step vs ~700 pipe work).
// R10: operands can't live in VGPRs (spill). Here each wave stages its OWN
// 64x64-quadrant operands (A slab 4 KB + B slab 4 KB per K-step) into a
// private 16 KB double-buffer via global_load_lds: no cross-wave sharing ->
// ZERO s_barrier in the loop; wave-local s_waitcnt vmcnt(8) paces the dbuf
// (issue PF(s+1)'s 8 loads, wait PF(s)'s 8, MFMA). Staging traffic doubles
// (row-pairs staged twice) but L2 absorbs it (~17 TB/s vs 34.5 ceiling).
// Same proven XOR chunk swizzle -> conflict-free frag ds_read_b64.
// LDS 64 KB -> 2 blocks/CU. Split-K=2, BK=64, 16 K-steps.
// grid (16,16,4), block 256.
// ---------------------------------------------------------------------------
__global__ __launch_bounds__(256, 2) void gemm_tri_kernel(
    const u8* __restrict__ A8, const u8* __restrict__ A8T,
    float* __restrict__ tri) {
  // wave w: [w*16384, +16384) = 2 bufs x (A 4 KB + B 4 KB).
  // epilogue reuses [0, 128*144=18432) as T tile.
  __shared__ __align__(16) u8 smem[65536];

  const int tid = threadIdx.x;
  const int w = tid >> 6, lane = tid & 63;
  const int wm = w >> 1, wn = w & 1;
  const int cl = lane & 15, g = lane >> 4;
  const int i0 = blockIdx.y * 128, j0 = blockIdx.x * 128;
  const int mz = blockIdx.z >> 1, kz = blockIdx.z & 1;
  const size_t mat = (size_t)mz * (NN * (size_t)NN);
  const u8* __restrict__ Am = A8 + mat;
  const u8* __restrict__ ATm = A8T + mat;
  float* __restrict__ triM = tri + mz * NN;
  u8* const wlds = smem + w * 16384;

  // staging: per operand 4 KB/step = 256 slots of 16 B; call c covers slots
  // c*64+lane. slot s -> row r = s>>2 (64 B rows), stored chunk c' = s&3
  // holds global chunk c_g = c' ^ ((r>>1)&3)  (XOR swizzle).
  const int kbase = kz * 1024;  // split-K half, bytes along K
  const u8* gA[4];
  const u8* gB[4];
#pragma unroll
  for (int c = 0; c < 4; ++c) {
    const int s = c * 64 + lane;
    const int r = s >> 2, cg = (s & 3) ^ ((r >> 1) & 3);
    gA[c] = Am + (size_t)(i0 + wm * 64 + r) * NN + kbase + cg * 16;
    gB[c] = ATm + (size_t)(j0 + wn * 64 + r) * NN + kbase + cg * 16;
  }

  // fragment read offsets (bytes, wave-local): row r = tm*16+cl, K-half h:
  // global chunk 2h+(g>>1) stored at ^((r>>1)&3) = ^((cl>>1)&3); sub (g&1)*8.
  const int rsw = (cl >> 1) & 3;
  const int sub = (g & 1) * 8, ch = g >> 1;
  int aoff[4][2], boff[4][2];
#pragma unroll
  for (int tm = 0; tm < 4; ++tm)
#pragma unroll
    for (int h = 0; h < 2; ++h) {
      aoff[tm][h] = (tm * 16 + cl) * 64 + (((2 * h + ch) ^ rsw) * 16) + sub;
      boff[tm][h] = 4096 + aoff[tm][h];
    }

  floatx4 acc[4][4] = {};

  // prime: step 0 -> buf 0
  PREFETCH(0, 0)

  // steps 0..14: issue PF(s+1) (8 loads), wait PF(s) (vmcnt(8)), MFMA(s).
  // NO barriers — wave-private data, wave-local pacing.
#pragma unroll 1
  for (int s = 0; s < 15; ++s) {
    const int pb = (s & 1) * 8192, pn = pb ^ 8192;
    FENCE;
    PREFETCH((s + 1) * 64, pn)
    __builtin_amdgcn_s_waitcnt(0x0F78);  // vmcnt(8): step-s loads landed
    FENCE;
    MFMA_BODY(pb)
  }
  FENCE;
  __builtin_amdgcn_s_waitcnt(0x0F70);  // vmcnt(0)
  FENCE;
  MFMA_BODY(8192)  // step 15 in buf1

  // epilogue: tri[i0+r] += sum_c C[r][c] * A^T[i0+r][j0+c]
  __syncthreads();
  // stage T: 128 rows x 128 B fp8, pitch 144 (16B-aligned, bank-spread)
#pragma unroll
  for (int it = 0; it < 4; ++it) {
    const int idx = tid + it * 256;
    const int r = idx >> 3, co = (idx & 7) * 16;
    *(uint4*)(smem + r * 144 + co) =
        *(const uint4*)(ATm + (size_t)(i0 + r) * NN + j0 + co);
  }
  __syncthreads();

#pragma unroll
  for (int tm = 0; tm < 4; ++tm) {
#pragma unroll
    for (int reg = 0; reg < 4; ++reg) {
      const int rloc = wm * 64 + tm * 16 + g * 4 + reg;  // C/D: row=(lane>>4)*4+reg
      float v = 0.f;
#pragma unroll
      for (int tn = 0; tn < 4; ++tn) {
        const int cloc = wn * 64 + tn * 16 + cl;          // C/D: col=lane&15
        // aligned-dword read: 4 lanes share an address -> LDS broadcast
        const unsigned dw =
            *(const unsigned*)(smem + rloc * 144 + (cloc & ~3));
        v += acc[tm][tn][reg] * fp8_to_f32((dw >> ((cloc & 3) * 8)) & 0xFFu);
      }
      v += __shfl_xor(v, 1);
      v += __shfl_xor(v, 2);
      v += __shfl_xor(v, 4);
      v += __shfl_xor(v, 8);
      if (cl == 0) atomicAdd(&triM[i0 + rloc], v);
    }
  }
}

// ---------------------------------------------------------------------------
// finalize stage 1: grid 16 x 1024 threads; block b reduces rows [b*128,+128).
// ---------------------------------------------------------------------------
__global__ __launch_bounds__(1024) void finalize1_kernel(
    const float* __restrict__ degp, const float* __restrict__ tri,
    float* __restrict__ part) {
  __shared__ float red[32];
  const int t = threadIdx.x;
  const int r = blockIdx.x * 128 + (t >> 3);   // row
  const int q = (t & 7) * 4;                   // degp chunk
  const float4 v1 = *(const float4*)(degp + (size_t)r * 32 + q);
  const float4 v2 = *(const float4*)(degp + 32 * NN + (size_t)r * 32 + q);
  float d1 = v1.x + v1.y + v1.z + v1.w;
  float d2 = v2.x + v2.y + v2.z + v2.w;
#pragma unroll
  for (int m = 1; m < 8; m <<= 1) {
    d1 += __shfl_xor(d1, m);
    d2 += __shfl_xor(d2, m);
  }
  float sdd = 0.f, scc = 0.f;
  if ((t & 7) == 0) {
    const float t1 = tri[r], t2 = tri[NN + r];
    const float e1 = d1 < 2.f ? 1.f : d1;
    const float e2 = d2 < 2.f ? 1.f : d2;
    sdd = fabsf(d1 - d2);
    scc = fabsf(t1 / (e1 * (e1 - 1.f)) - t2 / (e2 * (e2 - 1.f)));
  }
#pragma unroll
  for (int m = 8; m < 64; m <<= 1) {
    sdd += __shfl_xor(sdd, m);
    scc += __shfl_xor(scc, m);
  }
  const int wv = t >> 6, ln = t & 63;
  if (ln == 0) { red[wv] = sdd; red[16 + wv] = scc; }
  __syncthreads();
  if (t == 0) {
    float a = 0.f, b = 0.f;
#pragma unroll
    for (int i = 0; i < 16; ++i) { a += red[i]; b += red[16 + i]; }
    part[blockIdx.x * 2 + 0] = a;
    part[blockIdx.x * 2 + 1] = b;
  }
}

__global__ void finalize2_kernel(const float* __restrict__ part,
                                 float* __restrict__ out) {
  if (threadIdx.x == 0) {
    float a = 0.f, b = 0.f;
#pragma unroll
    for (int i = 0; i < 16; ++i) { a += part[i * 2]; b += part[i * 2 + 1]; }
    const float ds = expf(-a * (1.f / (float)NN));
    const float cs = expf(-b * (1.f / (float)NN));
    out[0] = ds;
    out[1] = cs;
    out[2] = 0.5f * (ds + cs);
  }
}

extern "C" void kernel_launch(void* const* d_in, const int* in_sizes, int n_in,
                              void* d_out, int out_size, void* d_ws, size_t ws_size,
                              hipStream_t stream) {
  (void)in_sizes; (void)n_in; (void)out_size; (void)ws_size;
  const float* A1 = (const float*)d_in[0];
  const float* A2 = (const float*)d_in[1];
  float* out = (float*)d_out;

  // workspace layout:
  //   A8   [2][2048*2048] u8  : 8 MB
  //   A8T  [2][2048*2048] u8  : 8 MB
  //   tri  [2][2048] f32
  //   degp [2][2048][32] f32
  //   part [32] f32
  u8* A8 = (u8*)d_ws;
  u8* A8T = A8 + 2 * (size_t)NN * NN;
  float* tri = (float*)(A8T + 2 * (size_t)NN * NN);
  float* degp = tri + 2 * NN;
  float* part = degp + 2 * 32 * NN;

  prep_kernel<<<dim3(32, 32, 2), 256, 0, stream>>>(A1, A2, A8, A8T, degp, tri);
  gemm_tri_kernel<<<dim3(16, 16, 4), 256, 0, stream>>>(A8, A8T, tri);
  finalize1_kernel<<<16, 1024, 0, stream>>>(degp, tri, part);
  finalize2_kernel<<<1, 64, 0, stream>>>(part, out);
}